// Round 8
// baseline (165.961 us; speedup 1.0000x reference)
//
#include <hip/hip_runtime.h>
#include <hip/hip_bf16.h>
#include <stdint.h>

// LoRAExpert: out = ragged_dot(x, W, groups) + scale[a] * ((x @ A[a,e]) @ B[a,e])
// T=8192, D_IN=D_OUT=1024, E=8 (equal groups of 1024), A=4 adapters, R=16.
// Inputs fp32, output fp32. ws = 256 MiB.
//
// Round 8 = BISECT: exact R5 base (passed, 165.5us) + ONLY the k_gemm
// 64x128 retile from R6. R6/R7 (merge+retile together) aborted twice; this
// isolates which change is at fault while keeping the retile's occupancy win.
//   k_prep : pack x->bf16 xp[:, :1024]; lora_A -> Aoct (scale folded);
//            W/lora_B -> Boct oct-interleaved.
//   k_vA   : V = xp @ Aoct[e] (MFMA, BK=64, swizzled A LDS), adapter-masked
//            -> xp[:, 1024:1088].
//   k_gemm : out = xp(K=1088) @ Boct[e], 64x128 tiles (1024 blocks, 4/CU),
//            BK=64, XOR-swizzled A tile, global_load_lds width 16.

#define T_TOK 8192
#define DIN   1024
#define DOUT  1024
#define NE    8
#define NA    4
#define RK    16
#define KEXT  1088      // 1024 + NA*RK
#define NOCT  136       // KEXT/8

typedef __attribute__((ext_vector_type(8))) short short8;
typedef __attribute__((ext_vector_type(4))) float f32x4;

__device__ __forceinline__ ushort f2bf(float f) {
  union { float f; uint32_t i; } v; v.f = f;
  uint32_t x = v.i;
  return (ushort)((x + 0x7fffu + ((x >> 16) & 1u)) >> 16);  // RNE
}

__device__ __forceinline__ void gload_lds16(const void* g, void* l) {
  __builtin_amdgcn_global_load_lds(
      (const __attribute__((address_space(1))) uint32_t*)g,
      (__attribute__((address_space(3))) uint32_t*)l,
      16, 0, 0);
}

__device__ __forceinline__ int expert_of_row(const int* __restrict__ gs, int row) {
  int cum = 0, e = 0;
#pragma unroll
  for (int i = 0; i < NE; ++i) { if (row >= cum) e = i; cum += gs[i]; }
  return e;
}

// ---- k_prep: all packing in one launch (verbatim R5) ----
// blocks [0, 8192)          : x -> bf16 xp[:, :1024]
// blocks [8192, 8448)       : lora_A -> Aoct[e][ko][c][8], scale folded
// blocks [8448, 9472)       : W -> Boct[e][ko<128][n][8]
// blocks [9472, 9536)       : lora_B -> Boct[e][128+o][n][8]
__global__ __launch_bounds__(256) void k_prep(
    const float* __restrict__ x, const float* __restrict__ weight,
    const float* __restrict__ lora_A, const float* __restrict__ lora_B,
    const float* __restrict__ lora_scaling,
    ushort* __restrict__ xp, ushort* __restrict__ Aoct, ushort* __restrict__ Boct) {
  const int bid = blockIdx.x;
  const int tid = threadIdx.x;

  if (bid < 8192) {                       // ---- pack x ----
    int idx = bid * 256 + tid;            // one float4 per thread
    int row = idx >> 8;                   // 256 float4 per row
    int c4 = idx & 255;
    float4 v = *(const float4*)(x + (size_t)row * DIN + c4 * 4);
    ushort4 b;
    b.x = f2bf(v.x); b.y = f2bf(v.y); b.z = f2bf(v.z); b.w = f2bf(v.w);
    *(ushort4*)(xp + (size_t)row * KEXT + c4 * 4) = b;
  } else if (bid < 8448) {                // ---- pack lora_A ----
    int u = (bid - 8192) * 4 + (tid >> 6);  // 0..1023 = e*128+ko
    int e = u >> 7, ko = u & 127;
    int c = tid & 63;
    int a = c >> 4, r = c & 15;
    float s = lora_scaling[a];
    ushort o8[8];
#pragma unroll
    for (int j = 0; j < 8; ++j) {
      float v = lora_A[((size_t)(a * NE + e) * DIN + ko * 8 + j) * RK + r];
      o8[j] = f2bf(s * v);
    }
    *(uint4*)(Aoct + ((size_t)((e * 128 + ko) * 64 + c)) * 8) = *(const uint4*)o8;
  } else {                                // ---- pack Boct ----
    int e, ko;
    const float* srcbase;
    int stride;
    if (bid < 9472) {                     // W rows
      int u = bid - 8448;                 // 0..1023
      e = u >> 7; ko = u & 127;
      srcbase = weight + (size_t)e * DIN * DOUT + (size_t)(ko * 8) * DOUT;
      stride = DOUT;
    } else {                              // lora_B rows
      int u = bid - 9472;                 // 0..63
      e = u >> 3; int o = u & 7; ko = 128 + o;
      srcbase = nullptr; stride = 0;
    }
    int n4 = tid * 4;
    float v[8][4];
    if (bid < 9472) {
#pragma unroll
      for (int j = 0; j < 8; ++j) {
        float4 q = *(const float4*)(srcbase + (size_t)j * stride + n4);
        v[j][0] = q.x; v[j][1] = q.y; v[j][2] = q.z; v[j][3] = q.w;
      }
    } else {
      int o = ko - 128;
#pragma unroll
      for (int j = 0; j < 8; ++j) {
        int kv = o * 8 + j;
        int a = kv >> 4, r = kv & 15;
        float4 q = *(const float4*)(lora_B + (size_t)((a * NE + e) * RK + r) * DOUT + n4);
        v[j][0] = q.x; v[j][1] = q.y; v[j][2] = q.z; v[j][3] = q.w;
      }
    }
    ushort* dst = Boct + ((size_t)(e * NOCT + ko) * DOUT + n4) * 8;
#pragma unroll
    for (int i = 0; i < 4; ++i) {
      ushort o8[8];
#pragma unroll
      for (int j = 0; j < 8; ++j) o8[j] = f2bf(v[j][i]);
      *(uint4*)(dst + i * 8) = *(const uint4*)o8;
    }
  }
}

// ---- k_vA: V = xp[:, :1024] @ Aoct[e], masked -> xp[:, 1024:1088] ----
// (verbatim R5) 128 blocks x 256 thr; tile 64 rows x 64 cols; BK=64.
__global__ __launch_bounds__(256) void k_vA(
    ushort* __restrict__ xp, const ushort* __restrict__ Aoct,
    const int* __restrict__ gs, const int* __restrict__ adapter_idx) {
  __shared__ ushort As2[64 * 64];     // 8 KB
  __shared__ ushort Bs2[8 * 64 * 8];  // 8 KB

  const int tid = threadIdx.x;
  const int lane = tid & 63;
  const int wave = tid >> 6;
  const int rows0 = blockIdx.x * 64;
  const int e = expert_of_row(gs, rows0);
  const ushort* aoct = Aoct + (size_t)e * 128 * 64 * 8;

  f32x4 acc[4];
#pragma unroll
  for (int ni = 0; ni < 4; ++ni) acc[ni] = (f32x4){0.f, 0.f, 0.f, 0.f};

  const int r8 = lane >> 3;                     // row-within-call 0..7
  const int c8s = (lane & 7) ^ r8;              // swizzled source chunk

  for (int kt = 0; kt < 16; ++kt) {
#pragma unroll
    for (int rd = 0; rd < 2; ++rd) {
      int row = wave * 16 + rd * 8 + r8;
      const ushort* src = xp + (size_t)(rows0 + row) * KEXT + kt * 64 + c8s * 8;
      gload_lds16(src, &As2[(wave * 16 + rd * 8) * 64]);
    }
#pragma unroll
    for (int rd = 0; rd < 2; ++rd) {
      int o = wave * 2 + rd;                    // local oct 0..7
      const ushort* src = aoct + ((size_t)(kt * 8 + o) * 64 + lane) * 8;
      gload_lds16(src, &Bs2[o * 64 * 8]);
    }
    __syncthreads();

    int m = wave * 16 + (lane & 15);
#pragma unroll
    for (int h = 0; h < 2; ++h) {
      int kblk = h * 4 + (lane >> 4);
      short8 af = *(const short8*)&As2[m * 64 + (kblk ^ (m & 7)) * 8];
#pragma unroll
      for (int ni = 0; ni < 4; ++ni) {
        short8 bfv = *(const short8*)&Bs2[(kblk * 64 + ni * 16 + (lane & 15)) * 8];
        acc[ni] = __builtin_amdgcn_mfma_f32_16x16x32_bf16(af, bfv, acc[ni], 0, 0, 0);
      }
    }
    __syncthreads();
  }

#pragma unroll
  for (int i = 0; i < 4; ++i) {
    int grow = rows0 + wave * 16 + (lane >> 4) * 4 + i;
    int a_row = adapter_idx[grow];
#pragma unroll
    for (int ni = 0; ni < 4; ++ni) {
      float val = (a_row == ni) ? acc[ni][i] : 0.f;
      xp[(size_t)grow * KEXT + DIN + ni * 16 + (lane & 15)] = f2bf(val);
    }
  }
}

// ---- k_gemm: out[64x128] = xp(64 x 1088) @ Boct[e](1088 x 128) ----
// RETILED (the R6 change under test): grid (8,128) = 1024 blocks (4/CU).
__global__ __launch_bounds__(256) void k_gemm(
    const ushort* __restrict__ xp, const ushort* __restrict__ Boct,
    const int* __restrict__ gs, float* __restrict__ out) {
  __shared__ ushort As[64 * 64 + 64];      // pad (harmless)
  __shared__ ushort Bs[8 * 128 * 8 + 64];

  const int tid = threadIdx.x;
  const int lane = tid & 63;
  const int wave = tid >> 6;
  const int wm = wave >> 1, wn = wave & 1;   // wave tile: 32 m x 64 n

  const int row0 = blockIdx.y * 64;
  const int n0 = blockIdx.x * 128;
  const int e = expert_of_row(gs, row0);
  const ushort* boct = Boct + (size_t)e * NOCT * DOUT * 8;

  f32x4 acc[2][4];
#pragma unroll
  for (int mi = 0; mi < 2; ++mi)
#pragma unroll
    for (int ni = 0; ni < 4; ++ni) acc[mi][ni] = (f32x4){0.f, 0.f, 0.f, 0.f};

  for (int kt = 0; kt < 17; ++kt) {
    // A: 64 rows x 8 chunks, 2 gload calls/wave, swizzled source
#pragma unroll
    for (int rd = 0; rd < 2; ++rd) {
      int id = wave * 128 + rd * 64 + lane;
      int r = id >> 3, c8 = id & 7;
      const ushort* src = xp + (size_t)(row0 + r) * KEXT + kt * 64 + (c8 ^ (r & 7)) * 8;
      gload_lds16(src, &As[(wave * 128 + rd * 64) * 8]);
    }
    // B: 8 octs x 128 n, 4 gload calls/wave, contiguous
#pragma unroll
    for (int rd = 0; rd < 4; ++rd) {
      int u = wave * 4 + rd;
      int o = u >> 1, hf = u & 1;
      const ushort* src = boct + ((size_t)(kt * 8 + o) * DOUT + n0 + hf * 64 + lane) * 8;
      gload_lds16(src, &Bs[(o * 128 + hf * 64) * 8]);
    }
    __syncthreads();

#pragma unroll
    for (int h = 0; h < 2; ++h) {
      int kblk = h * 4 + (lane >> 4);
      short8 af[2], bfv[4];
#pragma unroll
      for (int mi = 0; mi < 2; ++mi) {
        int m = wm * 32 + mi * 16 + (lane & 15);
        af[mi] = *(const short8*)&As[m * 64 + (kblk ^ (m & 7)) * 8];
      }
#pragma unroll
      for (int ni = 0; ni < 4; ++ni) {
        int n = wn * 64 + ni * 16 + (lane & 15);
        bfv[ni] = *(const short8*)&Bs[(kblk * 128 + n) * 8];
      }
#pragma unroll
      for (int mi = 0; mi < 2; ++mi)
#pragma unroll
        for (int ni = 0; ni < 4; ++ni)
          acc[mi][ni] = __builtin_amdgcn_mfma_f32_16x16x32_bf16(
              af[mi], bfv[ni], acc[mi][ni], 0, 0, 0);
    }
    __syncthreads();
  }

  // epilogue: C layout col=lane&15, row=(lane>>4)*4+reg
#pragma unroll
  for (int mi = 0; mi < 2; ++mi) {
#pragma unroll
    for (int ni = 0; ni < 4; ++ni) {
      int col = n0 + wn * 64 + ni * 16 + (lane & 15);
#pragma unroll
      for (int i = 0; i < 4; ++i) {
        int row = row0 + wm * 32 + mi * 16 + (lane >> 4) * 4 + i;
        out[(size_t)row * DOUT + col] = acc[mi][ni][i];
      }
    }
  }
}

extern "C" void kernel_launch(void* const* d_in, const int* in_sizes, int n_in,
                              void* d_out, int out_size, void* d_ws, size_t ws_size,
                              hipStream_t stream) {
  const float* x            = (const float*)d_in[0];
  const float* weight       = (const float*)d_in[1];
  const float* lora_A       = (const float*)d_in[2];
  const float* lora_B       = (const float*)d_in[3];
  const float* lora_scaling = (const float*)d_in[4];
  const int*   group_sizes  = (const int*)d_in[5];
  const int*   adapter_idx  = (const int*)d_in[6];
  float* out = (float*)d_out;

  const size_t sz_xp    = (size_t)T_TOK * KEXT * 2;              // 17.8 MB
  const size_t sz_boct  = (size_t)NE * NOCT * DOUT * 8 * 2;      // 17.8 MB
  ushort* xp   = (ushort*)d_ws;
  ushort* boct = (ushort*)((char*)d_ws + sz_xp);
  ushort* aoct = (ushort*)((char*)d_ws + sz_xp + sz_boct);       // 1 MB

  k_prep<<<9536, 256, 0, stream>>>(x, weight, lora_A, lora_B, lora_scaling,
                                   xp, aoct, boct);
  k_vA<<<T_TOK / 64, 256, 0, stream>>>(xp, aoct, group_sizes, adapter_idx);
  dim3 grid(DOUT / 128, T_TOK / 64);
  k_gemm<<<grid, 256, 0, stream>>>(xp, boct, group_sizes, out);
}